// Round 1
// baseline (1970.863 us; speedup 1.0000x reference)
//
#include <hip/hip_runtime.h>
#include <hip/hip_bf16.h>
#include <stdint.h>
#include <stddef.h>

typedef __attribute__((ext_vector_type(8))) short  short8;
typedef __attribute__((ext_vector_type(4))) short  short4v;
typedef __attribute__((ext_vector_type(4))) float  floatx4;
typedef __attribute__((ext_vector_type(4))) int    int4v;

static constexpr int MDIM = 8192;    // B*S = 4*2048
static constexpr int NDIM = 16384;   // OUT
static constexpr int KDIM = 4096;    // IN
static constexpr int BM = 128, BN = 128, BK = 32;

__device__ __forceinline__ unsigned short f32_to_bf16_rne(float f) {
    union { float f; unsigned u; } v; v.f = f;
    unsigned r = v.u + 0x7fffu + ((v.u >> 16) & 1u);
    return (unsigned short)(r >> 16);
}

// ---------------- conversion kernels (fast path) ----------------

__global__ __launch_bounds__(256) void cvt_x_bf16(const float* __restrict__ x,
                                                  unsigned short* __restrict__ o) {
    size_t i = ((size_t)blockIdx.x * 256 + threadIdx.x) * 8;
    floatx4 a = *(const floatx4*)(x + i);
    floatx4 b = *(const floatx4*)(x + i + 4);
    short8 r;
    r[0] = (short)f32_to_bf16_rne(a[0]);
    r[1] = (short)f32_to_bf16_rne(a[1]);
    r[2] = (short)f32_to_bf16_rne(a[2]);
    r[3] = (short)f32_to_bf16_rne(a[3]);
    r[4] = (short)f32_to_bf16_rne(b[0]);
    r[5] = (short)f32_to_bf16_rne(b[1]);
    r[6] = (short)f32_to_bf16_rne(b[2]);
    r[7] = (short)f32_to_bf16_rne(b[3]);
    *(short8*)(o + i) = r;
}

__global__ __launch_bounds__(256) void cvt_w_bf16(const int* __restrict__ w,
                                                  unsigned short* __restrict__ o) {
    size_t i = ((size_t)blockIdx.x * 256 + threadIdx.x) * 8;
    int4v a = *(const int4v*)(w + i);
    int4v b = *(const int4v*)(w + i + 4);
    short8 r;
    // codes in [-64,63] are exact in bf16 — no quantization error
    r[0] = (short)f32_to_bf16_rne((float)a[0]);
    r[1] = (short)f32_to_bf16_rne((float)a[1]);
    r[2] = (short)f32_to_bf16_rne((float)a[2]);
    r[3] = (short)f32_to_bf16_rne((float)a[3]);
    r[4] = (short)f32_to_bf16_rne((float)b[0]);
    r[5] = (short)f32_to_bf16_rne((float)b[1]);
    r[6] = (short)f32_to_bf16_rne((float)b[2]);
    r[7] = (short)f32_to_bf16_rne((float)b[3]);
    *(short8*)(o + i) = r;
}

// ---------------- async global->LDS helper ----------------

__device__ __forceinline__ void global_to_lds16(const unsigned short* g, unsigned short* l) {
    __builtin_amdgcn_global_load_lds(
        (__attribute__((address_space(1))) void*)(uintptr_t)g,
        (__attribute__((address_space(3))) void*)l,
        16, 0, 0);
}

// ---------------- main GEMM: C[m,n] = (sum_k A[m,k]*B[n,k]) * scale[n] + bias[n] ----------------
// A: [M,K] bf16 row-major, B: [N,K] bf16 row-major (i.e. B^T input, m97 structure)

__global__ __launch_bounds__(256) void gemm_bf16_bt(
        const unsigned short* __restrict__ A,
        const unsigned short* __restrict__ Bm,
        const float* __restrict__ scale,
        const float* __restrict__ bias,
        float* __restrict__ C) {
    __shared__ __align__(16) unsigned short sA[BM * BK];   // 8 KiB
    __shared__ __align__(16) unsigned short sB[BN * BK];   // 8 KiB

    const int tid = threadIdx.x;
    const int wv  = tid >> 6;        // wave 0..3
    const int ln  = tid & 63;
    const int bm  = blockIdx.y;
    const int bn  = blockIdx.x;
    const int wm  = wv >> 1;         // 2x2 wave grid, each wave owns 64x64
    const int wn  = wv & 1;

    // staging: each instr covers 64 rows (wave covers 16 rows: 64 lanes x 16B, 64B/row)
    const int srow = wv * 16 + (ln >> 2);
    const int scol = (ln & 3) * 8;
    const unsigned short* gA0 = A  + (size_t)(bm * BM + srow) * KDIM + scol;
    const unsigned short* gA1 = gA0 + (size_t)64 * KDIM;
    const unsigned short* gB0 = Bm + (size_t)(bn * BN + srow) * KDIM + scol;
    const unsigned short* gB1 = gB0 + (size_t)64 * KDIM;
    unsigned short* lA0 = sA + (wv * 16) * BK;        // wave-uniform LDS bases
    unsigned short* lA1 = sA + (64 + wv * 16) * BK;
    unsigned short* lB0 = sB + (wv * 16) * BK;
    unsigned short* lB1 = sB + (64 + wv * 16) * BK;

    // fragment read offsets: A[m=ln&15][k=quad*8+j], same shape for B^T rows
    const int aoff = (wm * 64 + (ln & 15)) * BK + (ln >> 4) * 8;
    const int boff = (wn * 64 + (ln & 15)) * BK + (ln >> 4) * 8;

    floatx4 acc[4][4];
    const floatx4 zero4 = {0.0f, 0.0f, 0.0f, 0.0f};
    #pragma unroll
    for (int i = 0; i < 4; ++i)
        #pragma unroll
        for (int j = 0; j < 4; ++j) acc[i][j] = zero4;

    for (int kt = 0; kt < KDIM; kt += BK) {
        global_to_lds16(gA0, lA0);
        global_to_lds16(gA1, lA1);
        global_to_lds16(gB0, lB0);
        global_to_lds16(gB1, lB1);
        gA0 += BK; gA1 += BK; gB0 += BK; gB1 += BK;
        __syncthreads();   // compiler emits vmcnt(0) drain before barrier

        short8 af[4], bfr[4];
        #pragma unroll
        for (int t = 0; t < 4; ++t) {
            af[t]  = *(const short8*)(sA + aoff + t * 16 * BK);
            bfr[t] = *(const short8*)(sB + boff + t * 16 * BK);
        }
        #pragma unroll
        for (int mt = 0; mt < 4; ++mt)
            #pragma unroll
            for (int nt = 0; nt < 4; ++nt)
                acc[mt][nt] = __builtin_amdgcn_mfma_f32_16x16x32_bf16(
                    af[mt], bfr[nt], acc[mt][nt], 0, 0, 0);
        __syncthreads();
    }

    // epilogue: C/D layout col=lane&15, row=quad*4+reg (m89/m91 verified)
    const int row0 = bm * BM + wm * 64 + (ln >> 4) * 4;
    const int col0 = bn * BN + wn * 64 + (ln & 15);
    #pragma unroll
    for (int nt = 0; nt < 4; ++nt) {
        const int col = col0 + nt * 16;
        const float sc = scale[col];
        const float bs = bias[col];
        #pragma unroll
        for (int mt = 0; mt < 4; ++mt) {
            float* cp = C + (size_t)(row0 + mt * 16) * NDIM + col;
            #pragma unroll
            for (int r = 0; r < 4; ++r)
                cp[(size_t)r * NDIM] = fmaf(acc[mt][nt][r], sc, bs);
        }
    }
}

// ---------------- fallback: fused convert+GEMM (used only if ws too small) ----------------

__global__ __launch_bounds__(256) void gemm_fused(
        const float* __restrict__ A,
        const int* __restrict__ W,
        const float* __restrict__ scale,
        const float* __restrict__ bias,
        float* __restrict__ C) {
    __shared__ __align__(16) unsigned short sA[BM * BK];
    __shared__ __align__(16) unsigned short sB[BN * BK];

    const int tid = threadIdx.x;
    const int wv = tid >> 6, ln = tid & 63;
    const int bm = blockIdx.y, bn = blockIdx.x;
    const int wm = wv >> 1, wn = wv & 1;
    const int aoff = (wm * 64 + (ln & 15)) * BK + (ln >> 4) * 8;
    const int boff = (wn * 64 + (ln & 15)) * BK + (ln >> 4) * 8;

    floatx4 acc[4][4];
    const floatx4 zero4 = {0.0f, 0.0f, 0.0f, 0.0f};
    #pragma unroll
    for (int i = 0; i < 4; ++i)
        #pragma unroll
        for (int j = 0; j < 4; ++j) acc[i][j] = zero4;

    for (int kt = 0; kt < KDIM; kt += BK) {
        __syncthreads();
        #pragma unroll
        for (int j = 0; j < 4; ++j) {
            int u = tid + j * 256;            // float4-unit index over 128x32 tile
            int row = u >> 3;
            int c4 = (u & 7) * 4;
            floatx4 av = *(const floatx4*)(A + (size_t)(bm * BM + row) * KDIM + kt + c4);
            short4v as;
            as[0] = (short)f32_to_bf16_rne(av[0]);
            as[1] = (short)f32_to_bf16_rne(av[1]);
            as[2] = (short)f32_to_bf16_rne(av[2]);
            as[3] = (short)f32_to_bf16_rne(av[3]);
            *(short4v*)(sA + row * BK + c4) = as;
            int4v wq = *(const int4v*)(W + (size_t)(bn * BN + row) * KDIM + kt + c4);
            short4v bs;
            bs[0] = (short)f32_to_bf16_rne((float)wq[0]);
            bs[1] = (short)f32_to_bf16_rne((float)wq[1]);
            bs[2] = (short)f32_to_bf16_rne((float)wq[2]);
            bs[3] = (short)f32_to_bf16_rne((float)wq[3]);
            *(short4v*)(sB + row * BK + c4) = bs;
        }
        __syncthreads();

        short8 af[4], bfr[4];
        #pragma unroll
        for (int t = 0; t < 4; ++t) {
            af[t]  = *(const short8*)(sA + aoff + t * 16 * BK);
            bfr[t] = *(const short8*)(sB + boff + t * 16 * BK);
        }
        #pragma unroll
        for (int mt = 0; mt < 4; ++mt)
            #pragma unroll
            for (int nt = 0; nt < 4; ++nt)
                acc[mt][nt] = __builtin_amdgcn_mfma_f32_16x16x32_bf16(
                    af[mt], bfr[nt], acc[mt][nt], 0, 0, 0);
    }

    const int row0 = bm * BM + wm * 64 + (ln >> 4) * 4;
    const int col0 = bn * BN + wn * 64 + (ln & 15);
    #pragma unroll
    for (int nt = 0; nt < 4; ++nt) {
        const int col = col0 + nt * 16;
        const float sc = scale[col];
        const float bs = bias[col];
        #pragma unroll
        for (int mt = 0; mt < 4; ++mt) {
            float* cp = C + (size_t)(row0 + mt * 16) * NDIM + col;
            #pragma unroll
            for (int r = 0; r < 4; ++r)
                cp[(size_t)r * NDIM] = fmaf(acc[mt][nt][r], sc, bs);
        }
    }
}

// ---------------- launch ----------------

extern "C" void kernel_launch(void* const* d_in, const int* in_sizes, int n_in,
                              void* d_out, int out_size, void* d_ws, size_t ws_size,
                              hipStream_t stream) {
    const float* x     = (const float*)d_in[0];
    const int*   w     = (const int*)d_in[1];
    const float* scale = (const float*)d_in[2];
    const float* bias  = (const float*)d_in[3];
    float* out = (float*)d_out;

    const size_t xElems = (size_t)MDIM * KDIM;   // 33,554,432 -> 64 MiB bf16
    const size_t wElems = (size_t)NDIM * KDIM;   // 67,108,864 -> 128 MiB bf16
    const size_t need   = (xElems + wElems) * sizeof(unsigned short);

    dim3 grid(NDIM / BN, MDIM / BM);   // (128, 64)

    if (ws_size >= need) {
        unsigned short* xb = (unsigned short*)d_ws;
        unsigned short* wb = xb + xElems;
        cvt_x_bf16<<<(unsigned)(xElems / (256 * 8)), 256, 0, stream>>>(x, xb);
        cvt_w_bf16<<<(unsigned)(wElems / (256 * 8)), 256, 0, stream>>>(w, wb);
        gemm_bf16_bt<<<grid, 256, 0, stream>>>(xb, wb, scale, bias, out);
    } else {
        gemm_fused<<<grid, 256, 0, stream>>>(x, w, scale, bias, out);
    }
}